// Round 1
// baseline (2572.377 us; speedup 1.0000x reference)
//
#include <hip/hip_runtime.h>

// Perona-Malik diffusion: 500 Jacobi iterations of a 5-pt stencil on [2,1,512,512] fp32.
// Baseline structure: one kernel launch per iteration (ping-pong buffers in d_ws),
// cv/ch computed once into d_out (they are outputs AND loop-invariant coefficients).

#define HH 512
#define WW 512
#define NB 2
#define NITER 500
static constexpr float LAM   = 0.24f;
static constexpr float KCOND = 0.03f;
static constexpr float DEPS_ = 0.1f;
static constexpr int IMG      = HH * WW;        // 262144
static constexpr int N_DEPTH  = NB * IMG;       // 524288
static constexpr int CV_PER_B = (HH - 1) * WW;  // 261632
static constexpr int CH_PER_B = HH * (WW - 1);  // 261632
static constexpr int N_CV     = NB * CV_PER_B;  // 523264
static constexpr int N_CH     = NB * CH_PER_B;  // 523264

// ---- monotone float<->uint key for atomic min over signed floats ----
__device__ __forceinline__ unsigned fkey(float f) {
    unsigned u = __float_as_uint(f);
    return (u & 0x80000000u) ? ~u : (u | 0x80000000u);
}
__device__ __forceinline__ float kinv(unsigned k) {
    return __uint_as_float((k & 0x80000000u) ? (k & 0x7fffffffu) : ~k);
}

__global__ void init_key_kernel(unsigned* key) { *key = 0xFFFFFFFFu; }

__global__ void min_kernel(const float* __restrict__ x, unsigned* key) {
    float m = 3.4e38f;
    for (int idx = blockIdx.x * blockDim.x + threadIdx.x; idx < N_DEPTH;
         idx += gridDim.x * blockDim.x)
        m = fminf(m, x[idx]);
    for (int off = 32; off > 0; off >>= 1) m = fminf(m, __shfl_down(m, off, 64));
    __shared__ float sm[4];
    int lane = threadIdx.x & 63, wv = threadIdx.x >> 6;
    if (lane == 0) sm[wv] = m;
    __syncthreads();
    if (threadIdx.x == 0) {
        float mm = fminf(fminf(sm[0], sm[1]), fminf(sm[2], sm[3]));
        atomicMin(key, fkey(mm));
    }
}

__global__ void shift_kernel(const unsigned* __restrict__ key, float* shift) {
    *shift = (kinv(*key) <= DEPS_) ? DEPS_ : 0.0f;
}

// cv[b,0,i,j] = g(mean_c |G[b,c,i+1,j]-G[b,c,i,j]|)   i<511
// ch[b,0,i,j] = g(mean_c |G[b,c,i,j+1]-G[b,c,i,j]|)   j<511
__global__ void coeff_kernel(const float* __restrict__ g, float* __restrict__ cv,
                             float* __restrict__ chh) {
    int idx = blockIdx.x * blockDim.x + threadIdx.x;
    constexpr float kk = KCOND * KCOND;
    if (idx < N_CV) {
        int b = idx / CV_PER_B;
        int r = idx - b * CV_PER_B;
        int i = r >> 9, j = r & (WW - 1);
        const float* gb = g + b * 3 * IMG + i * WW + j;
        float s = 0.f;
#pragma unroll
        for (int c = 0; c < 3; ++c) s += fabsf(gb[c * IMG + WW] - gb[c * IMG]);
        float m = s / 3.0f;
        cv[idx] = 1.0f / (1.0f + (m * m) / kk);
    } else if (idx < N_CV + N_CH) {
        int t = idx - N_CV;
        int b = t / CH_PER_B;
        int r = t - b * CH_PER_B;
        int i = r / (WW - 1);
        int j = r - i * (WW - 1);
        const float* gb = g + b * 3 * IMG + i * WW + j;
        float s = 0.f;
#pragma unroll
        for (int c = 0; c < 3; ++c) s += fabsf(gb[c * IMG + 1] - gb[c * IMG]);
        float m = s / 3.0f;
        chh[t] = 1.0f / (1.0f + (m * m) / kk);
    }
}

__global__ void init_depth_kernel(const float* __restrict__ ini,
                                  const float* __restrict__ shift,
                                  float* __restrict__ A) {
    int idx = blockIdx.x * blockDim.x + threadIdx.x;
    if (idx < N_DEPTH) A[idx] = ini[idx] + shift[0];
}

// One Jacobi step. Matches reference add order: -tv_up, +tv_dn, -th_left, +th_rt.
template <bool FINAL>
__global__ void step_kernel(const float* __restrict__ src, float* __restrict__ dst,
                            const float* __restrict__ cv, const float* __restrict__ chh,
                            const float* __restrict__ shift) {
    int idx = blockIdx.x * blockDim.x + threadIdx.x;
    if (idx >= N_DEPTH) return;
    int b = idx >> 18;
    int r = idx & (IMG - 1);
    int i = r >> 9;
    int j = r & (WW - 1);
    float c = src[idx];
    float v = c;
    const float* cvb = cv + b * CV_PER_B;
    const float* chb = chh + b * CH_PER_B;
    if (i > 0)      v -= (LAM * cvb[(i - 1) * WW + j]) * (c - src[idx - WW]);
    if (i < HH - 1) v += (LAM * cvb[i * WW + j]) * (src[idx + WW] - c);
    if (j > 0)      v -= (LAM * chb[i * (WW - 1) + j - 1]) * (c - src[idx - 1]);
    if (j < WW - 1) v += (LAM * chb[i * (WW - 1) + j]) * (src[idx + 1] - c);
    if (FINAL) v -= shift[0];
    dst[idx] = v;
}

extern "C" void kernel_launch(void* const* d_in, const int* in_sizes, int n_in,
                              void* d_out, int out_size, void* d_ws, size_t ws_size,
                              hipStream_t stream) {
    const float* guide   = (const float*)d_in[0];
    const float* initial = (const float*)d_in[1];
    float* out    = (float*)d_out;
    float* out_y  = out;                   // [2,1,512,512]
    float* out_cv = out + N_DEPTH;         // [2,1,511,512]
    float* out_ch = out + N_DEPTH + N_CV;  // [2,1,512,511]

    float* wsf      = (float*)d_ws;
    unsigned* key   = (unsigned*)d_ws;  // wsf[0]
    float* shift    = wsf + 1;
    float* bufA     = wsf + 64;         // 256 B offset, 2 MB
    float* bufB     = bufA + N_DEPTH;   // 2 MB

    hipLaunchKernelGGL(init_key_kernel, dim3(1), dim3(1), 0, stream, key);
    hipLaunchKernelGGL(min_kernel, dim3(256), dim3(256), 0, stream, initial, key);
    hipLaunchKernelGGL(shift_kernel, dim3(1), dim3(1), 0, stream, key, shift);

    int nco = N_CV + N_CH;
    hipLaunchKernelGGL(coeff_kernel, dim3((nco + 255) / 256), dim3(256), 0, stream,
                       guide, out_cv, out_ch);
    hipLaunchKernelGGL(init_depth_kernel, dim3((N_DEPTH + 255) / 256), dim3(256), 0,
                       stream, initial, shift, bufA);

    float* src = bufA;
    float* dst = bufB;
    for (int k = 0; k < NITER - 1; ++k) {
        hipLaunchKernelGGL((step_kernel<false>), dim3(N_DEPTH / 256), dim3(256), 0,
                           stream, src, dst, out_cv, out_ch, shift);
        float* t = src; src = dst; dst = t;
    }
    // 500th step: write y = depth - shift straight into d_out
    hipLaunchKernelGGL((step_kernel<true>), dim3(N_DEPTH / 256), dim3(256), 0, stream,
                       src, out_y, out_cv, out_ch, shift);
}

// Round 2
// 1098.943 us; speedup vs baseline: 2.3408x; 2.3408x over previous
//
#include <hip/hip_runtime.h>

// Perona-Malik diffusion, 500 iterations fused 10-at-a-time via LDS temporal blocking.
// 256 blocks; each owns a 64x32 interior tile, computes on an 88x52 region (halo>=10).
// Values + coefficients live in registers; ping-pong region buffers in LDS.

#define HH 512
#define WW 512
#define NB 2
static constexpr float LAM   = 0.24f;
static constexpr float KCOND = 0.03f;
static constexpr float DEPS_ = 0.1f;
static constexpr int IMG      = HH * WW;
static constexpr int N_DEPTH  = NB * IMG;
static constexpr int CV_PER_B = (HH - 1) * WW;   // 261632
static constexpr int CH_PER_B = HH * (WW - 1);   // 261632
static constexpr int N_CV     = NB * CV_PER_B;
static constexpr int N_CH     = NB * CH_PER_B;

static constexpr int T_FUSE = 10;                 // fused iterations per launch (50 x 10 = 500)
static constexpr int TILE_W = 64, TILE_H = 32;    // interior tile
static constexpr int HALO_X = 12, HALO_Y = 10;    // halo_x padded to multiple of 4
static constexpr int RW = TILE_W + 2 * HALO_X;    // 88
static constexpr int RH = TILE_H + 2 * HALO_Y;    // 52
static constexpr int NQ_ROW = RW / 4;             // 22 quads per row
static constexpr int NQUAD  = NQ_ROW * RH;        // 1144
static constexpr int QPT    = (NQUAD + 255) / 256; // 5 quads per thread (some inactive)
static constexpr int SSZ    = (RH + 2) * RW;      // region + 2 guard rows

// ---- monotone float<->uint key for atomic min ----
__device__ __forceinline__ unsigned fkey(float f) {
    unsigned u = __float_as_uint(f);
    return (u & 0x80000000u) ? ~u : (u | 0x80000000u);
}
__device__ __forceinline__ float kinv(unsigned k) {
    return __uint_as_float((k & 0x80000000u) ? (k & 0x7fffffffu) : ~k);
}

__global__ void init_key_kernel(unsigned* key) { *key = 0xFFFFFFFFu; }

__global__ void min_kernel(const float* __restrict__ x, unsigned* key) {
    float m = 3.4e38f;
    for (int idx = blockIdx.x * blockDim.x + threadIdx.x; idx < N_DEPTH;
         idx += gridDim.x * blockDim.x)
        m = fminf(m, x[idx]);
    for (int off = 32; off > 0; off >>= 1) m = fminf(m, __shfl_down(m, off, 64));
    __shared__ float sm[4];
    int lane = threadIdx.x & 63, wv = threadIdx.x >> 6;
    if (lane == 0) sm[wv] = m;
    __syncthreads();
    if (threadIdx.x == 0) {
        float mm = fminf(fminf(sm[0], sm[1]), fminf(sm[2], sm[3]));
        atomicMin(key, fkey(mm));
    }
}

// cv/ch outputs (unscaled, straight into d_out)
__global__ void coeff_kernel(const float* __restrict__ g, float* __restrict__ cv,
                             float* __restrict__ chh) {
    int idx = blockIdx.x * blockDim.x + threadIdx.x;
    constexpr float kk = KCOND * KCOND;
    if (idx < N_CV) {
        int b = idx / CV_PER_B;
        int r = idx - b * CV_PER_B;
        int i = r >> 9, j = r & (WW - 1);
        const float* gb = g + b * 3 * IMG + i * WW + j;
        float s = 0.f;
#pragma unroll
        for (int c = 0; c < 3; ++c) s += fabsf(gb[c * IMG + WW] - gb[c * IMG]);
        float m = s / 3.0f;
        cv[idx] = 1.0f / (1.0f + (m * m) / kk);
    } else if (idx < N_CV + N_CH) {
        int t = idx - N_CV;
        int b = t / CH_PER_B;
        int r = t - b * CH_PER_B;
        int i = r / (WW - 1);
        int j = r - i * (WW - 1);
        const float* gb = g + b * 3 * IMG + i * WW + j;
        float s = 0.f;
#pragma unroll
        for (int c = 0; c < 3; ++c) s += fabsf(gb[c * IMG + 1] - gb[c * IMG]);
        float m = s / 3.0f;
        chh[t] = 1.0f / (1.0f + (m * m) / kk);
    }
}

template <bool ADD_SHIFT, bool SUB_SHIFT>
__global__ __launch_bounds__(256, 1) void step_fused(
    const float* __restrict__ src, float* __restrict__ dst,
    const float* __restrict__ cv_g, const float* __restrict__ ch_g,
    const unsigned* __restrict__ key) {
    __shared__ float sb[2][SSZ];

    const int blk = blockIdx.x;
    const int b   = blk >> 7;            // batch image
    const int t   = blk & 127;           // tile within image: 16 rows x 8 cols of tiles
    const int y0  = (t >> 3) * TILE_H;
    const int x0  = (t & 7) * TILE_W;
    const float* cvb  = cv_g + b * CV_PER_B;
    const float* chb  = ch_g + b * CH_PER_B;
    const float* srcb = src + b * IMG;
    float*       dstb = dst + b * IMG;

    float shift = 0.f;
    if (ADD_SHIFT || SUB_SHIFT) shift = (kinv(*key) <= DEPS_) ? DEPS_ : 0.f;

    const int tid = threadIdx.x;

    float v[QPT][4];                      // current values (registers)
    float cu[QPT][4], cd[QPT][4];         // L*cv up/down per pixel
    float chq[QPT][5];                    // L*ch for the 5 edges of the quad
    int   roff[QPT];
    int   rr[QPT], xx[QPT];
    bool  act[QPT];

#pragma unroll
    for (int q = 0; q < QPT; ++q) {
        int qi  = tid + q * 256;
        act[q]  = qi < NQUAD;
        int qc  = act[q] ? qi : 0;
        int r   = qc / NQ_ROW;
        int x   = (qc - r * NQ_ROW) * 4;
        rr[q] = r; xx[q] = x;
        roff[q] = (r + 1) * RW + x;       // +1: top guard row
        int gy  = y0 - HALO_Y + r;
        int gx  = x0 - HALO_X + x;
        bool gy_in = (gy >= 0) && (gy < HH);
#pragma unroll
        for (int j = 0; j < 4; ++j) {
            int  gxx = gx + j;
            bool gx_in = (gxx >= 0) && (gxx < WW);
            bool vin = act[q] && gy_in && gx_in;
            float val = vin ? srcb[gy * WW + gxx] : 0.f;
            if (ADD_SHIFT) val += shift;
            v[q][j] = vin ? val : 0.f;
            bool up_ok = act[q] && (r >= 1) && (gy >= 1) && (gy < HH) && gx_in;
            cu[q][j] = up_ok ? LAM * cvb[(gy - 1) * WW + gxx] : 0.f;
            bool dn_ok = act[q] && (r <= RH - 2) && (gy >= 0) && (gy < HH - 1) && gx_in;
            cd[q][j] = dn_ok ? LAM * cvb[gy * WW + gxx] : 0.f;
        }
#pragma unroll
        for (int jj = 0; jj < 5; ++jj) {
            int  xe  = x + jj;            // region col of edge's right pixel
            int  gxe = gx + jj;           // global col of edge's right pixel
            bool ok = act[q] && (xe >= 1) && (xe <= RW - 1) && gy_in &&
                      (gxe >= 1) && (gxe < WW);
            chq[q][jj] = ok ? LAM * chb[gy * (WW - 1) + (gxe - 1)] : 0.f;
        }
    }

    // zero guard rows (top + bottom) of both buffers
    for (int i = tid; i < RW; i += 256) {
        sb[0][i] = 0.f; sb[0][(RH + 1) * RW + i] = 0.f;
        sb[1][i] = 0.f; sb[1][(RH + 1) * RW + i] = 0.f;
    }
    // initial values into buffer 0
#pragma unroll
    for (int q = 0; q < QPT; ++q)
        if (act[q])
            *reinterpret_cast<float4*>(&sb[0][roff[q]]) =
                float4{v[q][0], v[q][1], v[q][2], v[q][3]};
    __syncthreads();

    int cur = 0;
    for (int it = 0; it < T_FUSE; ++it) {
        float nv[QPT][4];
#pragma unroll
        for (int q = 0; q < QPT; ++q) {
            const float* s = sb[cur];
            float4 up = *reinterpret_cast<const float4*>(&s[roff[q] - RW]);
            float4 dn = *reinterpret_cast<const float4*>(&s[roff[q] + RW]);
            float  lf = s[roff[q] - 1];
            float  rt = s[roff[q] + 4];
            float c0 = v[q][0], c1 = v[q][1], c2 = v[q][2], c3 = v[q][3];
            nv[q][0] = c0 - cu[q][0] * (c0 - up.x) + cd[q][0] * (dn.x - c0)
                          - chq[q][0] * (c0 - lf) + chq[q][1] * (c1 - c0);
            nv[q][1] = c1 - cu[q][1] * (c1 - up.y) + cd[q][1] * (dn.y - c1)
                          - chq[q][1] * (c1 - c0) + chq[q][2] * (c2 - c1);
            nv[q][2] = c2 - cu[q][2] * (c2 - up.z) + cd[q][2] * (dn.z - c2)
                          - chq[q][2] * (c2 - c1) + chq[q][3] * (c3 - c2);
            nv[q][3] = c3 - cu[q][3] * (c3 - up.w) + cd[q][3] * (dn.w - c3)
                          - chq[q][3] * (c3 - c2) + chq[q][4] * (rt - c3);
        }
        int nxt = cur ^ 1;
#pragma unroll
        for (int q = 0; q < QPT; ++q) {
            if (act[q])
                *reinterpret_cast<float4*>(&sb[nxt][roff[q]]) =
                    float4{nv[q][0], nv[q][1], nv[q][2], nv[q][3]};
            v[q][0] = nv[q][0]; v[q][1] = nv[q][1];
            v[q][2] = nv[q][2]; v[q][3] = nv[q][3];
        }
        cur = nxt;
        __syncthreads();
    }

    // write back interior only (exact after T_FUSE steps)
#pragma unroll
    for (int q = 0; q < QPT; ++q) {
        if (!act[q]) continue;
        int r = rr[q], x = xx[q];
        if (r >= HALO_Y && r < HALO_Y + TILE_H && x >= HALO_X && x < HALO_X + TILE_W) {
            int gy = y0 - HALO_Y + r;
            int gx = x0 - HALO_X + x;
            float4 o{v[q][0], v[q][1], v[q][2], v[q][3]};
            if (SUB_SHIFT) { o.x -= shift; o.y -= shift; o.z -= shift; o.w -= shift; }
            *reinterpret_cast<float4*>(&dstb[gy * WW + gx]) = o;
        }
    }
}

extern "C" void kernel_launch(void* const* d_in, const int* in_sizes, int n_in,
                              void* d_out, int out_size, void* d_ws, size_t ws_size,
                              hipStream_t stream) {
    const float* guide   = (const float*)d_in[0];
    const float* initial = (const float*)d_in[1];
    float* out    = (float*)d_out;
    float* out_y  = out;
    float* out_cv = out + N_DEPTH;
    float* out_ch = out + N_DEPTH + N_CV;

    unsigned* key = (unsigned*)d_ws;
    float* wsf    = (float*)d_ws;
    float* bufA   = wsf + 64;
    float* bufB   = bufA + N_DEPTH;

    hipLaunchKernelGGL(init_key_kernel, dim3(1), dim3(1), 0, stream, key);
    hipLaunchKernelGGL(min_kernel, dim3(256), dim3(256), 0, stream, initial, key);

    int nco = N_CV + N_CH;
    hipLaunchKernelGGL(coeff_kernel, dim3((nco + 255) / 256), dim3(256), 0, stream,
                       guide, out_cv, out_ch);

    constexpr int NLAUNCH = 50;  // 50 x T_FUSE = 500
    float* bufs[2] = {bufA, bufB};
    for (int k = 0; k < NLAUNCH; ++k) {
        const float* src = (k == 0) ? initial : bufs[(k + 1) & 1];
        float*       dst = (k == NLAUNCH - 1) ? out_y : bufs[k & 1];
        if (k == 0)
            hipLaunchKernelGGL((step_fused<true, false>), dim3(256), dim3(256), 0,
                               stream, src, dst, out_cv, out_ch, key);
        else if (k == NLAUNCH - 1)
            hipLaunchKernelGGL((step_fused<false, true>), dim3(256), dim3(256), 0,
                               stream, src, dst, out_cv, out_ch, key);
        else
            hipLaunchKernelGGL((step_fused<false, false>), dim3(256), dim3(256), 0,
                               stream, src, dst, out_cv, out_ch, key);
    }
}